// Round 14
// baseline (246.650 us; speedup 1.0000x reference)
//
#include <hip/hip_runtime.h>
#include <math.h>

#define NB 16
#define NN 24
#define NA 384       /* atoms total */
#define FF 128
#define CC 27
#define MAXNBR 32    /* physically <= 23 possible (image spacing L > 2r) */

// ---- static device scratch (d_ws unused). g_arrF is zero at load and reset by the
// unique final block of each batch every call -> clean state per graph replay.
__device__ int   g_cnt[NA];
__device__ float g_sigma[4];
__device__ int   g_nj[NA*MAXNBR];
__device__ float g_nd[NA*MAXNBR];
__device__ float g_nw[NA*MAXNBR];
__device__ float g_featA[NA*FF];    // feat0
__device__ float g_featB[NA*FF];    // feat1
__device__ float g_projA[NA*4*FF];  // P0 (K1/K2), then P2 (agent-scope, K3)
__device__ float g_projB[NA*4*FF];  // P1
__device__ float g_feat2[NA*FF];    // feat2 (agent-scope)
__device__ int   g_arrF[NB];        // last-arrival counter

__device__ __forceinline__ float softplusf(float x){ return fmaxf(x,0.f) + log1pf(expf(-fabsf(x))); }
__device__ __forceinline__ float sigmoidf(float x){ return 1.f/(1.f+expf(-x)); }
__device__ __forceinline__ void st_agent(float* p, float v){
  __hip_atomic_store(p, v, __ATOMIC_RELAXED, __HIP_MEMORY_SCOPE_AGENT);
}
__device__ __forceinline__ float ld_agent(const float* p){
  return __hip_atomic_load(p, __ATOMIC_RELAXED, __HIP_MEMORY_SCOPE_AGENT);
}

// ============ K1: sigma (blocks 0-2) | per-atom feat0 + nbr list + P0 (blocks 3+) ============
__global__ void __launch_bounds__(512)
k_prep(const float* __restrict__ pos, const float* __restrict__ cell,
       const float* __restrict__ emb, const float* __restrict__ fc_W,
       const float* __restrict__ conv_Wf, const float* __restrict__ conv_Ws,
       const int* __restrict__ z)
{
  const int bid = blockIdx.x, tid = threadIdx.x;
  const int q = tid >> 7, f = tid & 127;

  if (bid < 3) {
    // ---- spectral-norm power iteration (5 iters, eps=1e-12), W in LDS stride 129 ----
    __shared__ float s_w[FF*129];
    __shared__ float s_u[FF], s_v[FF], s_red[FF];
    __shared__ float s_part[4][FF];
    const float* W = fc_W + bid*FF*FF;
    for (int idx = tid; idx < FF*FF; idx += 512)
      s_w[(idx >> 7)*129 + (idx & 127)] = W[idx];          // coalesced
    if (tid < FF) s_u[tid] = 0.08838834764831845f;         // 1/sqrt(128)
    __syncthreads();
    for (int it = 0; it < 5; it++) {
      { float p = 0.f;                                      // v = W u (k-split)
        #pragma unroll
        for (int k = q*32; k < q*32+32; k++) p += s_w[f*129+k]*s_u[k];
        s_part[q][f] = p; }
      __syncthreads();
      if (tid < FF) { float s = s_part[0][f]+s_part[1][f]+s_part[2][f]+s_part[3][f];
                      s_v[f] = s; s_red[f] = s*s; }
      __syncthreads();
      for (int st=64; st>0; st>>=1){ if (tid<st) s_red[tid]+=s_red[tid+st]; __syncthreads(); }
      float nv = sqrtf(s_red[0]) + 1e-12f;
      __syncthreads();
      if (tid < FF) s_v[f] /= nv;
      __syncthreads();
      { float p = 0.f;                                      // u = W^T v (r-split)
        #pragma unroll
        for (int r = q*32; r < q*32+32; r++) p += s_w[r*129+f]*s_v[r];
        s_part[q][f] = p; }
      __syncthreads();
      if (tid < FF) { float s = s_part[0][f]+s_part[1][f]+s_part[2][f]+s_part[3][f];
                      s_u[f] = s; s_red[f] = s*s; }
      __syncthreads();
      for (int st=64; st>0; st>>=1){ if (tid<st) s_red[tid]+=s_red[tid+st]; __syncthreads(); }
      float nu = sqrtf(s_red[0]) + 1e-12f;
      __syncthreads();
      if (tid < FF) s_u[f] /= nu;
      __syncthreads();
    }
    { float p = 0.f;                                        // sigma = v . (W u)
      #pragma unroll
      for (int k = q*32; k < q*32+32; k++) p += s_w[f*129+k]*s_u[k];
      s_part[q][f] = p; }
    __syncthreads();
    if (tid < FF) s_red[f] = s_v[f]*(s_part[0][f]+s_part[1][f]+s_part[2][f]+s_part[3][f]);
    __syncthreads();
    for (int st=64; st>0; st>>=1){ if (tid<st) s_red[tid]+=s_red[tid+st]; __syncthreads(); }
    if (tid == 0) g_sigma[bid] = s_red[0];
  } else {
    // ---- one atom per block: feat0, radius, neighbor list, then P0 ----
    const int i = bid - 3;
    const int b = i / NN;
    __shared__ float ft[FF];
    __shared__ float s_cell[9];
    __shared__ float s_rb;
    __shared__ int   s_cnt;
    if (tid < FF) {
      int zi = z[i]; if (zi < 1) zi = 1; if (zi > 100) zi = 100;
      float v = tanhf(emb[(zi-1)*FF+tid]);
      ft[tid] = v;
      g_featA[i*FF+tid] = v;
    }
    if (tid >= 256 && tid < 265) s_cell[tid-256] = cell[b*9 + tid - 256];
    if (tid == 500) s_cnt = 0;
    __syncthreads();
    if (tid == 0) {
      const float* c = s_cell;
      float cx = c[4]*c[8] - c[5]*c[7];
      float cy = c[5]*c[6] - c[3]*c[8];
      float cz = c[3]*c[7] - c[4]*c[6];
      float vol = c[0]*cx + c[1]*cy + c[2]*cz;
      s_rb = cbrtf(fabsf(vol)/(float)NN);               // RADIUS_RATE = 1
    }
    __syncthreads();
    const float rb = s_rb, rb2 = rb*rb;
    const float pix = pos[i*3+0], piy = pos[i*3+1], piz = pos[i*3+2];
    const float PI = 3.14159265358979323846f;
    for (int cand = tid; cand < NN*CC; cand += 512) {
      int j = cand / CC, c = cand - j*CC;
      float gx = (float)(c/9) - 1.0f;
      float gy = (float)((c/3)%3) - 1.0f;
      float gz = (float)(c%3) - 1.0f;
      float ox = gx*s_cell[0] + gy*s_cell[3] + gz*s_cell[6];
      float oy = gx*s_cell[1] + gy*s_cell[4] + gz*s_cell[7];
      float oz = gx*s_cell[2] + gy*s_cell[5] + gz*s_cell[8];
      int jg = b*NN + j;
      float dx = pix - (pos[jg*3+0] + ox);
      float dy = piy - (pos[jg*3+1] + oy);
      float dz = piz - (pos[jg*3+2] + oz);
      float d2 = dx*dx + dy*dy + dz*dz;
      if (d2 <= rb2 && d2 > 1e-4f) {
        float dist = sqrtf(fmaxf(d2, 1e-12f));
        float w = cosf(dist*PI/rb) + 1.0f;
        int slot = atomicAdd(&s_cnt, 1);                // block-local
        if (slot < MAXNBR) {
          g_nj[i*MAXNBR+slot] = jg;
          g_nd[i*MAXNBR+slot] = dist;
          g_nw[i*MAXNBR+slot] = w;
        }
      }
    }
    __syncthreads();
    if (tid == 0) g_cnt[i] = (s_cnt > MAXNBR) ? MAXNBR : s_cnt;
    // ---- P0: quarter q computes one of {gi,gj,si,sj} ----
    const float* W = (q==0) ? conv_Wf
                   : (q==1) ? (conv_Wf + FF*FF)
                   : (q==2) ? conv_Ws
                   :          (conv_Ws + FF*FF);
    float s = 0.f;
    #pragma unroll 8
    for (int k=0;k<FF;k++) s += ft[k]*W[k*FF+f];
    g_projA[(i*4+q)*FF+f] = s;
  }
}

// ============ K2: E0 (+ fused P1) ============
__global__ void __launch_bounds__(512)
k_edge0(const float* __restrict__ conv_Wf, const float* __restrict__ conv_bf,
        const float* __restrict__ conv_Ws, const float* __restrict__ conv_bs)
{
  const int i = blockIdx.x, tid = threadIdx.x;
  const int q = tid >> 7, f = tid & 127;
  const float* Wf2 = conv_Wf + 2*FF*FF;   // layer 0: Wf[2F:]
  const float* Ws2 = conv_Ws + 2*FF*FF;

  const float gi  = g_projA[(i*4+0)*FF+f];
  const float si  = g_projA[(i*4+2)*FF+f];
  const float bff = conv_bf[f];
  const float bsf = conv_bs[f];
  const float step  = 6.0f/127.0f;
  const float coeff = -0.5f/(step*step);
  const int n = g_cnt[i];

  float msg = 0.f;
  for (int e = q; e < n; e += 4) {
    const int   jg   = g_nj[i*MAXNBR+e];
    const float dist = g_nd[i*MAXNBR+e];
    const float w    = g_nw[i*MAXNBR+e];
    const float gj   = g_projA[(jg*4+1)*FF+f];
    const float sj   = g_projA[(jg*4+3)*FF+f];
    // banded Gaussian: |dist-k*step|>9*step terms < 2e-18 (exact in fp32; validated R4-R13)
    float center = dist / step;
    int kmin = (int)ceilf(center - 9.0f);  if (kmin < 0)   kmin = 0;
    int kmax = (int)floorf(center + 9.0f); if (kmax > 127) kmax = 127;
    float ge = 0.f, se = 0.f;
    for (int k = kmin; k <= kmax; k++) {
      float dd = dist - step*(float)k;
      float a  = expf(coeff*dd*dd);
      ge += a * Wf2[k*FF+f];
      se += a * Ws2[k*FF+f];
    }
    msg += sigmoidf(gi + gj + ge + bff) * softplusf(si + sj + se + bsf) * w;
  }

  __shared__ float sm[4][FF];
  __shared__ float fnew[FF];
  sm[q][f] = msg;
  __syncthreads();
  if (tid < FF) {
    float v = softplusf(g_featA[i*FF+f] + sm[0][f] + sm[1][f] + sm[2][f] + sm[3][f]);
    fnew[f] = v;
    g_featB[i*FF+f] = v;                 // feat1
  }
  __syncthreads();
  // fused P1 -> projB
  const float* WfN = conv_Wf + 3*FF*FF;
  const float* WsN = conv_Ws + 3*FF*FF;
  const float* W = (q==0) ? WfN : (q==1) ? (WfN + FF*FF) : (q==2) ? WsN : (WsN + FF*FF);
  float s = 0.f;
  #pragma unroll 8
  for (int k=0;k<FF;k++) s += fnew[k]*W[k*FF+f];
  g_projB[(i*4+q)*FF+f] = s;
}

// ====== K3: E1 + P2 (per atom, wide) + last-arriving block runs E2-for-batch + FC tail ======
__global__ void __launch_bounds__(512)
k_tail(const float* __restrict__ conv_Wf, const float* __restrict__ conv_bf,
       const float* __restrict__ conv_Ws, const float* __restrict__ conv_bs,
       const float* __restrict__ fc_W,  const float* __restrict__ fc_b,
       const float* __restrict__ W_out, const float* __restrict__ b_out,
       float* __restrict__ out)
{
  const int i = blockIdx.x, tid = threadIdx.x;
  const int q = tid >> 7, f = tid & 127;
  const int b = i / NN;
  const float step  = 6.0f/127.0f;
  const float coeff = -0.5f/(step*step);

  __shared__ float sm[4][FF];
  __shared__ float fnew[FF];
  __shared__ int   s_old;

  // ---- E1 (neighbor P1 from g_projB via normal loads; produced last dispatch) ----
  {
    const float* Wf2 = conv_Wf + 1*3*FF*FF + 2*FF*FF;
    const float* Ws2 = conv_Ws + 1*3*FF*FF + 2*FF*FF;
    const float gi  = g_projB[(i*4+0)*FF+f];
    const float si  = g_projB[(i*4+2)*FF+f];
    const float bff = conv_bf[1*FF+f];
    const float bsf = conv_bs[1*FF+f];
    const int n = g_cnt[i];
    float msg = 0.f;
    for (int e = q; e < n; e += 4) {
      const int   jg   = g_nj[i*MAXNBR+e];
      const float dist = g_nd[i*MAXNBR+e];
      const float w    = g_nw[i*MAXNBR+e];
      const float gj   = g_projB[(jg*4+1)*FF+f];
      const float sj   = g_projB[(jg*4+3)*FF+f];
      float center = dist / step;
      int kmin = (int)ceilf(center - 9.0f);  if (kmin < 0)   kmin = 0;
      int kmax = (int)floorf(center + 9.0f); if (kmax > 127) kmax = 127;
      float ge = 0.f, se = 0.f;
      for (int k = kmin; k <= kmax; k++) {
        float dd = dist - step*(float)k;
        float a  = expf(coeff*dd*dd);
        ge += a * Wf2[k*FF+f];
        se += a * Ws2[k*FF+f];
      }
      msg += sigmoidf(gi + gj + ge + bff) * softplusf(si + sj + se + bsf) * w;
    }
    sm[q][f] = msg;
    __syncthreads();
    if (tid < FF)
      fnew[f] = softplusf(g_featB[i*FF+f] + sm[0][f]+sm[1][f]+sm[2][f]+sm[3][f]);  // feat2
    __syncthreads();
  }

  // ---- P2 -> g_projA + feat2 -> g_feat2 (agent-scope stores) ----
  {
    const float* WfN = conv_Wf + 2*3*FF*FF;
    const float* WsN = conv_Ws + 2*3*FF*FF;
    const float* W = (q==0) ? WfN : (q==1) ? (WfN+FF*FF) : (q==2) ? WsN : (WsN+FF*FF);
    float s = 0.f;
    #pragma unroll 8
    for (int k=0;k<FF;k++) s += fnew[k]*W[k*FF+f];
    st_agent(&g_projA[(i*4+q)*FF+f], s);
    if (tid < FF) st_agent(&g_feat2[i*FF+f], fnew[f]);
  }
  asm volatile("s_waitcnt vmcnt(0)" ::: "memory");   // own stores at LLC
  __syncthreads();                                    // whole block drained
  if (tid == 0)
    s_old = __hip_atomic_fetch_add(&g_arrF[b], 1, __ATOMIC_ACQ_REL,
                                   __HIP_MEMORY_SCOPE_AGENT);
  __syncthreads();
  if (s_old != NN-1) return;                   // not the last block of this batch

  // ---------- unique last block of batch b: E2 for all 24 atoms + mean + FC + head ----------
  // All 24 blocks' P2/feat2 are at LLC (each drained before its arrival bump).
  __shared__ float s_mean[4][FF];
  __shared__ float s_hh[FF], s_tmp[FF], s_part[4][FF], s_red[FF];
  {
    const float* Wf2 = conv_Wf + 2*3*FF*FF + 2*FF*FF;
    const float* Ws2 = conv_Ws + 2*3*FF*FF + 2*FF*FF;
    const float bff = conv_bf[2*FF+f];
    const float bsf = conv_bs[2*FF+f];
    float acc = 0.f;
    for (int a = q; a < NN; a += 4) {            // group q owns 6 atoms
      const int ag = b*NN + a;
      const float gi = ld_agent(&g_projA[(ag*4+0)*FF+f]);
      const float si = ld_agent(&g_projA[(ag*4+2)*FF+f]);
      const int n = g_cnt[ag];
      float msg = 0.f;
      for (int e = 0; e < n; e++) {
        const int   jg   = g_nj[ag*MAXNBR+e];
        const float dist = g_nd[ag*MAXNBR+e];
        const float w    = g_nw[ag*MAXNBR+e];
        const float gj   = ld_agent(&g_projA[(jg*4+1)*FF+f]);
        const float sj   = ld_agent(&g_projA[(jg*4+3)*FF+f]);
        float center = dist / step;
        int kmin = (int)ceilf(center - 9.0f);  if (kmin < 0)   kmin = 0;
        int kmax = (int)floorf(center + 9.0f); if (kmax > 127) kmax = 127;
        float ge = 0.f, se = 0.f;
        for (int k = kmin; k <= kmax; k++) {
          float dd = dist - step*(float)k;
          float a2 = expf(coeff*dd*dd);
          ge += a2 * Wf2[k*FF+f];
          se += a2 * Ws2[k*FF+f];
        }
        msg += sigmoidf(gi + gj + ge + bff) * softplusf(si + sj + se + bsf) * w;
      }
      acc += softplusf(ld_agent(&g_feat2[ag*FF+f]) + msg);  // final feat of atom ag
    }
    s_mean[q][f] = acc;                          // slot owned by this thread
  }
  __syncthreads();
  if (tid < FF)
    s_hh[f] = (s_mean[0][f]+s_mean[1][f]+s_mean[2][f]+s_mean[3][f]) / (float)NN;
  __syncthreads();
  for (int l = 0; l < 3; l++) {
    { float p = 0.f;
      #pragma unroll
      for (int k = q*32; k < q*32+32; k++) p += s_hh[k]*fc_W[l*FF*FF + k*FF + f];
      s_part[q][f] = p; }
    __syncthreads();
    if (tid < FF) {
      float s = s_part[0][tid]+s_part[1][tid]+s_part[2][tid]+s_part[3][tid];
      s_tmp[tid] = softplusf(s/g_sigma[l] + fc_b[l*FF+tid]);
    }
    __syncthreads();
    if (tid < FF) s_hh[tid] = s_tmp[tid];
    __syncthreads();
  }
  if (tid < FF) s_red[tid] = s_hh[tid]*W_out[tid];
  __syncthreads();
  if (tid < 64) {
    float t = s_red[tid] + s_red[tid+64];
    #pragma unroll
    for (int off = 32; off > 0; off >>= 1) t += __shfl_xor(t, off);
    if (tid == 0) {
      out[b] = t + b_out[0];
      __hip_atomic_store(&g_arrF[b], 0, __ATOMIC_RELAXED,
                         __HIP_MEMORY_SCOPE_AGENT);   // reset for next replay
    }
  }
}

extern "C" void kernel_launch(void* const* d_in, const int* in_sizes, int n_in,
                              void* d_out, int out_size, void* d_ws, size_t ws_size,
                              hipStream_t stream) {
  const float* pos     = (const float*)d_in[0];
  const float* cell    = (const float*)d_in[1];
  const float* emb     = (const float*)d_in[2];
  const float* conv_Wf = (const float*)d_in[3];
  const float* conv_bf = (const float*)d_in[4];
  const float* conv_Ws = (const float*)d_in[5];
  const float* conv_bs = (const float*)d_in[6];
  const float* fc_W    = (const float*)d_in[7];
  const float* fc_b    = (const float*)d_in[8];
  const float* W_out   = (const float*)d_in[9];
  const float* b_out   = (const float*)d_in[10];
  const int*   z       = (const int*)d_in[11];
  // d_in[12] = batch (unused); d_ws unused. All tensors fp32 (validated R3-R13).

  k_prep <<<NA+3, 512, 0, stream>>>(pos, cell, emb, fc_W, conv_Wf, conv_Ws, z);
  k_edge0<<<NA,   512, 0, stream>>>(conv_Wf, conv_bf, conv_Ws, conv_bs);
  k_tail <<<NA,   512, 0, stream>>>(conv_Wf, conv_bf, conv_Ws, conv_bs,
                                    fc_W, fc_b, W_out, b_out, (float*)d_out);
}

// Round 15
// 139.836 us; speedup vs baseline: 1.7639x; 1.7639x over previous
//
#include <hip/hip_runtime.h>
#include <math.h>

#define NB 16
#define NN 24
#define NA 384       /* atoms total */
#define FF 128
#define CC 27
#define MAXNBR 32    /* physically <= 23 possible (image spacing L > 2r) */

// ---- static device scratch (d_ws unused). g_arrF is zero at load and reset by the
// unique final block of each batch every call -> clean state per graph replay.
__device__ int   g_cnt[NA];
__device__ float g_sigma[4];
__device__ int   g_nj[NA*MAXNBR];
__device__ float g_nd[NA*MAXNBR];
__device__ float g_nw[NA*MAXNBR];
__device__ float g_featA[NA*FF];    // feat0, then feat2
__device__ float g_featB[NA*FF];    // feat1
__device__ float g_projA[NA*4*FF];  // P0, then P2
__device__ float g_projB[NA*4*FF];  // P1
__device__ float g_feat [NA*FF];    // final feats (agent-scope)
__device__ int   g_arrF[NB];        // last-arrival counter for the FC tail

__device__ __forceinline__ float softplusf(float x){ return fmaxf(x,0.f) + log1pf(expf(-fabsf(x))); }
__device__ __forceinline__ float sigmoidf(float x){ return 1.f/(1.f+expf(-x)); }
__device__ __forceinline__ void st_agent(float* p, float v){
  __hip_atomic_store(p, v, __ATOMIC_RELAXED, __HIP_MEMORY_SCOPE_AGENT);
}
__device__ __forceinline__ float ld_agent(const float* p){
  return __hip_atomic_load(p, __ATOMIC_RELAXED, __HIP_MEMORY_SCOPE_AGENT);
}

// Fixed-trip banded Gaussian dot: 20 fully-unrolled terms covering the +-9*step band.
// Terms outside the true band have gauss < 2e-18 -> invisible in fp32 sums.
__device__ __forceinline__ void band_dot(float dist, const float* __restrict__ Wf2,
                                         const float* __restrict__ Ws2, int f,
                                         float& ge, float& se)
{
  const float step  = 6.0f/127.0f;
  const float coeff = -0.5f/(step*step);
  int kmin = (int)ceilf(dist/step - 9.0f);
  kmin = kmin < 0 ? 0 : (kmin > 108 ? 108 : kmin);
  float g = 0.f, s = 0.f;
  #pragma unroll
  for (int t = 0; t < 20; t++) {
    int k = kmin + t;
    float dd = dist - step*(float)k;
    float a  = expf(coeff*dd*dd);
    g += a * Wf2[k*FF+f];
    s += a * Ws2[k*FF+f];
  }
  ge = g; se = s;
}

// ============ K1: sigma (blocks 0-2) | per-atom feat0 + nbr list + P0 (blocks 3+) ============
__global__ void __launch_bounds__(512)
k_prep(const float* __restrict__ pos, const float* __restrict__ cell,
       const float* __restrict__ emb, const float* __restrict__ fc_W,
       const float* __restrict__ conv_Wf, const float* __restrict__ conv_Ws,
       const int* __restrict__ z)
{
  const int bid = blockIdx.x, tid = threadIdx.x;
  const int q = tid >> 7, f = tid & 127;

  if (bid < 3) {
    // ---- spectral-norm power iteration (5 iters, eps=1e-12), W in LDS stride 129 ----
    __shared__ float s_w[FF*129];
    __shared__ float s_u[FF], s_v[FF], s_red[FF];
    __shared__ float s_part[4][FF];
    const float* W = fc_W + bid*FF*FF;
    for (int idx = tid; idx < FF*FF; idx += 512)
      s_w[(idx >> 7)*129 + (idx & 127)] = W[idx];          // coalesced
    if (tid < FF) s_u[tid] = 0.08838834764831845f;         // 1/sqrt(128)
    __syncthreads();
    for (int it = 0; it < 5; it++) {
      { float p = 0.f;                                      // v = W u (k-split)
        #pragma unroll
        for (int k = q*32; k < q*32+32; k++) p += s_w[f*129+k]*s_u[k];
        s_part[q][f] = p; }
      __syncthreads();
      if (tid < FF) { float s = s_part[0][f]+s_part[1][f]+s_part[2][f]+s_part[3][f];
                      s_v[f] = s; s_red[f] = s*s; }
      __syncthreads();
      for (int st=64; st>0; st>>=1){ if (tid<st) s_red[tid]+=s_red[tid+st]; __syncthreads(); }
      float nv = sqrtf(s_red[0]) + 1e-12f;
      __syncthreads();
      if (tid < FF) s_v[f] /= nv;
      __syncthreads();
      { float p = 0.f;                                      // u = W^T v (r-split)
        #pragma unroll
        for (int r = q*32; r < q*32+32; r++) p += s_w[r*129+f]*s_v[r];
        s_part[q][f] = p; }
      __syncthreads();
      if (tid < FF) { float s = s_part[0][f]+s_part[1][f]+s_part[2][f]+s_part[3][f];
                      s_u[f] = s; s_red[f] = s*s; }
      __syncthreads();
      for (int st=64; st>0; st>>=1){ if (tid<st) s_red[tid]+=s_red[tid+st]; __syncthreads(); }
      float nu = sqrtf(s_red[0]) + 1e-12f;
      __syncthreads();
      if (tid < FF) s_u[f] /= nu;
      __syncthreads();
    }
    { float p = 0.f;                                        // sigma = v . (W u)
      #pragma unroll
      for (int k = q*32; k < q*32+32; k++) p += s_w[f*129+k]*s_u[k];
      s_part[q][f] = p; }
    __syncthreads();
    if (tid < FF) s_red[f] = s_v[f]*(s_part[0][f]+s_part[1][f]+s_part[2][f]+s_part[3][f]);
    __syncthreads();
    for (int st=64; st>0; st>>=1){ if (tid<st) s_red[tid]+=s_red[tid+st]; __syncthreads(); }
    if (tid == 0) g_sigma[bid] = s_red[0];
  } else {
    // ---- one atom per block: feat0, radius, neighbor list, then P0 ----
    const int i = bid - 3;
    const int b = i / NN;
    __shared__ float ft[FF];
    __shared__ float s_cell[9];
    __shared__ float s_rb;
    __shared__ int   s_cnt;
    if (tid < FF) {
      int zi = z[i]; if (zi < 1) zi = 1; if (zi > 100) zi = 100;
      float v = tanhf(emb[(zi-1)*FF+tid]);
      ft[tid] = v;
      g_featA[i*FF+tid] = v;
    }
    if (tid >= 256 && tid < 265) s_cell[tid-256] = cell[b*9 + tid - 256];
    if (tid == 500) s_cnt = 0;
    __syncthreads();
    if (tid == 0) {
      const float* c = s_cell;
      float cx = c[4]*c[8] - c[5]*c[7];
      float cy = c[5]*c[6] - c[3]*c[8];
      float cz = c[3]*c[7] - c[4]*c[6];
      float vol = c[0]*cx + c[1]*cy + c[2]*cz;
      s_rb = cbrtf(fabsf(vol)/(float)NN);               // RADIUS_RATE = 1
    }
    __syncthreads();
    const float rb = s_rb, rb2 = rb*rb;
    const float pix = pos[i*3+0], piy = pos[i*3+1], piz = pos[i*3+2];
    const float PI = 3.14159265358979323846f;
    for (int cand = tid; cand < NN*CC; cand += 512) {
      int j = cand / CC, c = cand - j*CC;
      float gx = (float)(c/9) - 1.0f;
      float gy = (float)((c/3)%3) - 1.0f;
      float gz = (float)(c%3) - 1.0f;
      float ox = gx*s_cell[0] + gy*s_cell[3] + gz*s_cell[6];
      float oy = gx*s_cell[1] + gy*s_cell[4] + gz*s_cell[7];
      float oz = gx*s_cell[2] + gy*s_cell[5] + gz*s_cell[8];
      int jg = b*NN + j;
      float dx = pix - (pos[jg*3+0] + ox);
      float dy = piy - (pos[jg*3+1] + oy);
      float dz = piz - (pos[jg*3+2] + oz);
      float d2 = dx*dx + dy*dy + dz*dz;
      if (d2 <= rb2 && d2 > 1e-4f) {
        float dist = sqrtf(fmaxf(d2, 1e-12f));
        float w = cosf(dist*PI/rb) + 1.0f;
        int slot = atomicAdd(&s_cnt, 1);                // block-local
        if (slot < MAXNBR) {
          g_nj[i*MAXNBR+slot] = jg;
          g_nd[i*MAXNBR+slot] = dist;
          g_nw[i*MAXNBR+slot] = w;
        }
      }
    }
    __syncthreads();
    if (tid == 0) g_cnt[i] = (s_cnt > MAXNBR) ? MAXNBR : s_cnt;
    // ---- P0: quarter q computes one of {gi,gj,si,sj} ----
    const float* W = (q==0) ? conv_Wf
                   : (q==1) ? (conv_Wf + FF*FF)
                   : (q==2) ? conv_Ws
                   :          (conv_Ws + FF*FF);
    float s = 0.f;
    #pragma unroll 16
    for (int k=0;k<FF;k++) s += ft[k]*W[k*FF+f];
    g_projA[(i*4+q)*FF+f] = s;
  }
}

// ============ K2/K3: edges of layer l (+ fused proj of layer l+1, double-buffered) ========
template<int LAYER>
__global__ void __launch_bounds__(512)
k_edge(const float* __restrict__ conv_Wf, const float* __restrict__ conv_bf,
       const float* __restrict__ conv_Ws, const float* __restrict__ conv_bs)
{
  const int i = blockIdx.x, tid = threadIdx.x;
  const int q = tid >> 7, f = tid & 127;
  const float* projSrc = (LAYER==0) ? g_projA : g_projB;
  float*       projDst = (LAYER==0) ? g_projB : g_projA;
  const float* fin  = (LAYER==0) ? g_featA : g_featB;
  float*       fout = (LAYER==0) ? g_featB : g_featA;
  const float* Wf2 = conv_Wf + LAYER*3*FF*FF + 2*FF*FF;
  const float* Ws2 = conv_Ws + LAYER*3*FF*FF + 2*FF*FF;

  const float gi  = projSrc[(i*4+0)*FF+f];
  const float si  = projSrc[(i*4+2)*FF+f];
  const float bff = conv_bf[LAYER*FF+f];
  const float bsf = conv_bs[LAYER*FF+f];
  const int n = g_cnt[i];

  float msg = 0.f;
  for (int e = q; e < n; e += 4) {
    const int   jg   = g_nj[i*MAXNBR+e];
    const float dist = g_nd[i*MAXNBR+e];
    const float w    = g_nw[i*MAXNBR+e];
    const float gj   = projSrc[(jg*4+1)*FF+f];
    const float sj   = projSrc[(jg*4+3)*FF+f];
    float ge, se;
    band_dot(dist, Wf2, Ws2, f, ge, se);
    msg += sigmoidf(gi + gj + ge + bff) * softplusf(si + sj + se + bsf) * w;
  }

  __shared__ float sm[4][FF];
  __shared__ float fnew[FF];
  sm[q][f] = msg;
  __syncthreads();
  if (tid < FF) {
    float v = softplusf(fin[i*FF+f] + sm[0][f] + sm[1][f] + sm[2][f] + sm[3][f]);
    fnew[f] = v;
    fout[i*FF+f] = v;
  }
  __syncthreads();
  // fused proj of layer LAYER+1
  const float* WfN = conv_Wf + (LAYER+1)*3*FF*FF;
  const float* WsN = conv_Ws + (LAYER+1)*3*FF*FF;
  const float* W = (q==0) ? WfN : (q==1) ? (WfN + FF*FF) : (q==2) ? WsN : (WsN + FF*FF);
  float s = 0.f;
  #pragma unroll 16
  for (int k=0;k<FF;k++) s += fnew[k]*W[k*FF+f];
  projDst[(i*4+q)*FF+f] = s;
}

// ============ K4: E2 + last-arriving-block does mean/FC/head (spin-free) ============
__global__ void __launch_bounds__(512)
k_edge2f(const float* __restrict__ conv_Wf, const float* __restrict__ conv_bf,
         const float* __restrict__ conv_Ws, const float* __restrict__ conv_bs,
         const float* __restrict__ fc_W,  const float* __restrict__ fc_b,
         const float* __restrict__ W_out, const float* __restrict__ b_out,
         float* __restrict__ out)
{
  const int i = blockIdx.x, tid = threadIdx.x;
  const int q = tid >> 7, f = tid & 127;
  const int b = i / NN;
  const float* Wf2 = conv_Wf + 2*3*FF*FF + 2*FF*FF;
  const float* Ws2 = conv_Ws + 2*3*FF*FF + 2*FF*FF;

  const float gi  = g_projA[(i*4+0)*FF+f];     // P2
  const float si  = g_projA[(i*4+2)*FF+f];
  const float bff = conv_bf[2*FF+f];
  const float bsf = conv_bs[2*FF+f];
  const int n = g_cnt[i];

  float msg = 0.f;
  for (int e = q; e < n; e += 4) {
    const int   jg   = g_nj[i*MAXNBR+e];
    const float dist = g_nd[i*MAXNBR+e];
    const float w    = g_nw[i*MAXNBR+e];
    const float gj   = g_projA[(jg*4+1)*FF+f];
    const float sj   = g_projA[(jg*4+3)*FF+f];
    float ge, se;
    band_dot(dist, Wf2, Ws2, f, ge, se);
    msg += sigmoidf(gi + gj + ge + bff) * softplusf(si + sj + se + bsf) * w;
  }

  __shared__ float sm[4][FF];
  __shared__ int   s_old;
  sm[q][f] = msg;
  __syncthreads();
  if (tid < FF) {
    // residual base = feat2 (g_featA)  [R11 bug fixed]
    float v = softplusf(g_featA[i*FF+f] + sm[0][f] + sm[1][f] + sm[2][f] + sm[3][f]);
    st_agent(&g_feat[i*FF+f], v);              // LLC-coherent store
  }
  asm volatile("s_waitcnt vmcnt(0)" ::: "memory");   // own stores at LLC
  __syncthreads();                                    // whole block drained
  if (tid == 0)
    s_old = __hip_atomic_fetch_add(&g_arrF[b], 1, __ATOMIC_ACQ_REL,
                                   __HIP_MEMORY_SCOPE_AGENT);
  __syncthreads();
  if (s_old != NN-1) return;                   // not the last block of this batch

  // ---------- unique last block of batch b: mean + FC chain + head ----------
  __shared__ float s_hh[FF], s_tmp[FF], s_part[4][FF], s_red[FF];
  if (tid < FF) {
    float s0 = 0.f;
    for (int a = 0; a < NN; a++) s0 += ld_agent(&g_feat[(b*NN+a)*FF+tid]);
    s_hh[tid] = s0/(float)NN;
  }
  __syncthreads();
  for (int l = 0; l < 3; l++) {
    { float p = 0.f;
      #pragma unroll
      for (int k = q*32; k < q*32+32; k++) p += s_hh[k]*fc_W[l*FF*FF + k*FF + f];
      s_part[q][f] = p; }
    __syncthreads();
    if (tid < FF) {
      float s = s_part[0][tid]+s_part[1][tid]+s_part[2][tid]+s_part[3][tid];
      s_tmp[tid] = softplusf(s/g_sigma[l] + fc_b[l*FF+tid]);
    }
    __syncthreads();
    if (tid < FF) s_hh[tid] = s_tmp[tid];
    __syncthreads();
  }
  if (tid < FF) s_red[tid] = s_hh[tid]*W_out[tid];
  __syncthreads();
  if (tid < 64) {
    float t = s_red[tid] + s_red[tid+64];
    #pragma unroll
    for (int off = 32; off > 0; off >>= 1) t += __shfl_xor(t, off);
    if (tid == 0) {
      out[b] = t + b_out[0];
      __hip_atomic_store(&g_arrF[b], 0, __ATOMIC_RELAXED,
                         __HIP_MEMORY_SCOPE_AGENT);   // reset for next replay
    }
  }
}

extern "C" void kernel_launch(void* const* d_in, const int* in_sizes, int n_in,
                              void* d_out, int out_size, void* d_ws, size_t ws_size,
                              hipStream_t stream) {
  const float* pos     = (const float*)d_in[0];
  const float* cell    = (const float*)d_in[1];
  const float* emb     = (const float*)d_in[2];
  const float* conv_Wf = (const float*)d_in[3];
  const float* conv_bf = (const float*)d_in[4];
  const float* conv_Ws = (const float*)d_in[5];
  const float* conv_bs = (const float*)d_in[6];
  const float* fc_W    = (const float*)d_in[7];
  const float* fc_b    = (const float*)d_in[8];
  const float* W_out   = (const float*)d_in[9];
  const float* b_out   = (const float*)d_in[10];
  const int*   z       = (const int*)d_in[11];
  // d_in[12] = batch (unused); d_ws unused. All tensors fp32 (validated R3-R14).

  k_prep   <<<NA+3, 512, 0, stream>>>(pos, cell, emb, fc_W, conv_Wf, conv_Ws, z);
  k_edge<0><<<NA,   512, 0, stream>>>(conv_Wf, conv_bf, conv_Ws, conv_bs);
  k_edge<1><<<NA,   512, 0, stream>>>(conv_Wf, conv_bf, conv_Ws, conv_bs);
  k_edge2f <<<NA,   512, 0, stream>>>(conv_Wf, conv_bf, conv_Ws, conv_bs,
                                      fc_W, fc_b, W_out, b_out, (float*)d_out);
}